// Round 1
// baseline (26.826 us; speedup 1.0000x reference)
//
#include <hip/hip_runtime.h>

// out[k][j] = max( x1[k][j], max_i( W[i][j]*x0[k][i] + B[i][j] + C_norm[i][j] ) )
// N=4096, D=256, all float32.

constexpr int Dk = 256;    // D
constexpr int BK = 32;     // k-rows per block
constexpr int BJ = 64;     // j-cols per block
constexpr int IB = 64;     // i-chunk staged per iteration
constexpr int X0S = IB + 4;  // padded row stride for x0 tile (keeps float4 align, breaks bank collisions)

__global__ __launch_bounds__(256, 2)
void fused_maxplus(const float* __restrict__ x0,
                   const float* __restrict__ x1,
                   const float* __restrict__ Cn,
                   const float* __restrict__ W,
                   const float* __restrict__ Bm,
                   float* __restrict__ out) {
    __shared__ float x0s[BK][X0S];   // x0s[kk][ii]
    __shared__ float Ws[IB][BJ];     // W tile  [ii][jj]
    __shared__ float As[IB][BJ];     // (B + C_norm) tile [ii][jj]

    const int tid = threadIdx.x;
    const int kb = blockIdx.x >> 2;      // 128 k-blocks
    const int jb = blockIdx.x & 3;       // 4 j-blocks
    const int k0 = kb * BK;
    const int j0 = jb * BJ;

    const int jg = tid & 15;             // 16 j-groups of 4
    const int kg = tid >> 4;             // 16 k-groups of 2
    const int jj = jg * 4;
    const int kk2 = kg * 2;

    float acc[2][4];
#pragma unroll
    for (int m = 0; m < 2; ++m)
#pragma unroll
        for (int n = 0; n < 4; ++n) acc[m][n] = -3.402823466e38f;

    for (int ic = 0; ic < Dk; ic += IB) {
        __syncthreads();   // protect previous chunk's LDS reads

        // ---- stage W tile and A = B + C tile (coalesced float4) ----
#pragma unroll
        for (int c = 0; c < 4; ++c) {
            const int idx = c * 256 + tid;   // 0..1023 -> 64 rows x 16 float4
            const int row = idx >> 4;
            const int col = (idx & 15) * 4;
            const int g = (ic + row) * Dk + j0 + col;
            const float4 wv = *reinterpret_cast<const float4*>(&W[g]);
            const float4 bv = *reinterpret_cast<const float4*>(&Bm[g]);
            const float4 cv = *reinterpret_cast<const float4*>(&Cn[g]);
            *reinterpret_cast<float4*>(&Ws[row][col]) = wv;
            const float4 av = make_float4(bv.x + cv.x, bv.y + cv.y,
                                          bv.z + cv.z, bv.w + cv.w);
            *reinterpret_cast<float4*>(&As[row][col]) = av;
        }
        // ---- stage x0 tile, un-transposed (coalesced float4, no transpose cost) ----
#pragma unroll
        for (int c = 0; c < 2; ++c) {
            const int idx = c * 256 + tid;   // 0..511 -> 32 rows x 16 float4
            const int kk = idx >> 4;
            const int ii0 = (idx & 15) * 4;
            const float4 v = *reinterpret_cast<const float4*>(&x0[(k0 + kk) * Dk + ic + ii0]);
            *reinterpret_cast<float4*>(&x0s[kk][ii0]) = v;
        }
        __syncthreads();

        // ---- inner compute: per 4 i's -> 10 ds_read_b128, 64 VALU ----
#pragma unroll 4
        for (int ii = 0; ii < IB; ii += 4) {
            const float4 xa = *reinterpret_cast<const float4*>(&x0s[kk2 + 0][ii]);
            const float4 xb = *reinterpret_cast<const float4*>(&x0s[kk2 + 1][ii]);
            const float xs[2][4] = {{xa.x, xa.y, xa.z, xa.w},
                                    {xb.x, xb.y, xb.z, xb.w}};
#pragma unroll
            for (int u = 0; u < 4; ++u) {
                const float4 wv = *reinterpret_cast<const float4*>(&Ws[ii + u][jj]);
                const float4 av = *reinterpret_cast<const float4*>(&As[ii + u][jj]);
                const float w4[4] = {wv.x, wv.y, wv.z, wv.w};
                const float a4[4] = {av.x, av.y, av.z, av.w};
#pragma unroll
                for (int m = 0; m < 2; ++m) {
#pragma unroll
                    for (int n = 0; n < 4; ++n) {
                        acc[m][n] = fmaxf(acc[m][n], fmaf(w4[n], xs[m][u], a4[n]));
                    }
                }
            }
        }
    }

    // ---- epilogue: fold in x1, store coalesced float4 ----
#pragma unroll
    for (int m = 0; m < 2; ++m) {
        const int k = k0 + kk2 + m;
        const int j = j0 + jj;
        const float4 xv = *reinterpret_cast<const float4*>(&x1[k * Dk + j]);
        float4 o;
        o.x = fmaxf(acc[m][0], xv.x);
        o.y = fmaxf(acc[m][1], xv.y);
        o.z = fmaxf(acc[m][2], xv.z);
        o.w = fmaxf(acc[m][3], xv.w);
        *reinterpret_cast<float4*>(&out[k * Dk + j]) = o;
    }
}

extern "C" void kernel_launch(void* const* d_in, const int* in_sizes, int n_in,
                              void* d_out, int out_size, void* d_ws, size_t ws_size,
                              hipStream_t stream) {
    const float* x0 = (const float*)d_in[0];
    const float* x1 = (const float*)d_in[1];
    const float* Cn = (const float*)d_in[2];
    const float* W  = (const float*)d_in[3];
    const float* Bm = (const float*)d_in[4];
    float* out = (float*)d_out;

    const int n = in_sizes[0] / Dk;            // 4096
    const int grid = (n / BK) * (Dk / BJ);     // 128 * 4 = 512
    hipLaunchKernelGGL(fused_maxplus, dim3(grid), dim3(256), 0, stream,
                       x0, x1, Cn, W, Bm, out);
}